// Round 4
// baseline (453.798 us; speedup 1.0000x reference)
//
#include <hip/hip_runtime.h>

#define NB    32
#define LQ    300
#define DM    256
#define NH    8
#define HD    32
#define NPTS  12
#define NCOLS 288   // 192 offset cols + 96 attn cols
#define STOT  8400
#define QB    8     // queries per block
#define NBQ   (NB * LQ)
#define NBLK  (NBQ / QB)   // 1200 blocks

static __device__ __forceinline__ float bf2f(unsigned short u) {
    union { unsigned int i; float f; } v;
    v.i = ((unsigned int)u) << 16;
    return v.f;
}

// Wave-0 dtype vote for one tensor. Lane t samples even ushort 2t.
// bf16 data -> exponent field almost always in [0x60,0x85]; fp32 data ->
// sampled ushorts are mantissa low-halves (uniform) -> ~85% implausible.
static __device__ __forceinline__ bool vote_f32(const void* p, int t) {
    const unsigned short u = ((const unsigned short*)p)[2 * t];
    const unsigned int e = (u >> 7) & 0xFFu;
    const bool bad = !(u == 0 || (e >= 0x60u && e <= 0x85u));
    return __popcll(__ballot(bad)) >= 16;
}

// ---------------------------------------------------------------------------
// Phase 1: projection of QB query rows against W_off|W_attn into proj_lds.
// Thread owns output column j; W loads lane-contiguous (coalesced), query
// rows broadcast from LDS as float4.
// ---------------------------------------------------------------------------
template<bool WF32>
static __device__ __forceinline__ void proj_cols(
    const void* __restrict__ Wo, const void* __restrict__ bo,
    const void* __restrict__ Wa, const void* __restrict__ ba,
    const float* __restrict__ q_lds, float* __restrict__ proj_lds, int tid)
{
    for (int j = tid; j < NCOLS; j += 256) {
        const void* Wp; const void* bp; int stride, jj;
        if (j < 192) { Wp = Wo; bp = bo; stride = 192; jj = j; }
        else         { Wp = Wa; bp = ba; stride = 96;  jj = j - 192; }

        float acc[QB];
#pragma unroll
        for (int q = 0; q < QB; ++q) acc[q] = 0.f;

        for (int k = 0; k < DM; k += 4) {
            float w[4];
#pragma unroll
            for (int kk = 0; kk < 4; ++kk) {
                const int wi = (k + kk) * stride + jj;
                w[kk] = WF32 ? ((const float*)Wp)[wi]
                             : bf2f(((const unsigned short*)Wp)[wi]);
            }
#pragma unroll
            for (int q = 0; q < QB; ++q) {
                const float4 qv = *(const float4*)&q_lds[q * DM + k];
                acc[q] = fmaf(qv.x, w[0],
                         fmaf(qv.y, w[1],
                         fmaf(qv.z, w[2],
                         fmaf(qv.w, w[3], acc[q]))));
            }
        }

        const float bias = WF32 ? ((const float*)bp)[jj]
                                : bf2f(((const unsigned short*)bp)[jj]);
#pragma unroll
        for (int q = 0; q < QB; ++q)
            proj_lds[q * NCOLS + j] = acc[q] + bias;
    }
}

// ---------------------------------------------------------------------------
// Phase 2: softmax + bilinear sampling + weighted sum for QB*128 tasks.
// Task = (q, head h, lane l); lane owns channels 2l, 2l+1 of head h.
// Output written as fp32 float2 (reference output dtype is float32).
// ---------------------------------------------------------------------------
template<bool VF32>
static __device__ __forceinline__ void sample_tasks(
    const void* __restrict__ value, const float* __restrict__ proj_lds,
    const float* __restrict__ ref_lds, float2* __restrict__ out,
    int q0, int tid)
{
#pragma unroll
    for (int it = 0; it < (QB * 128) / 256; ++it) {
        const int task = it * 256 + tid;
        const int q = task >> 7;
        const int h = (task >> 4) & 7;
        const int l = task & 15;
        const int bq = q0 + q;
        const int b  = bq / LQ;
        const float* pr = proj_lds + q * NCOLS;

        // softmax over 12 attention logits of head h (redundant per 16 lanes)
        float a[NPTS];
#pragma unroll
        for (int p = 0; p < NPTS; ++p) a[p] = pr[192 + h * NPTS + p];
        float m = a[0];
#pragma unroll
        for (int p = 1; p < NPTS; ++p) m = fmaxf(m, a[p]);
        float s = 0.f;
#pragma unroll
        for (int p = 0; p < NPTS; ++p) { a[p] = __expf(a[p] - m); s += a[p]; }
        const float inv = 1.f / s;

        const float rx = ref_lds[q * 4 + 0];
        const float ry = ref_lds[q * 4 + 1];
        const float rw = ref_lds[q * 4 + 2];
        const float rh = ref_lds[q * 4 + 3];

        // element offset of (b, cell 0, head h, channels 2l..2l+1)
        const size_t base_e = (size_t)b * STOT * DM + h * HD + l * 2;
        const unsigned int* vb16 = (const unsigned int*)value + (base_e >> 1);
        const float2*       vb32 = (const float2*)value + (base_e >> 1);

        float acc0 = 0.f, acc1 = 0.f;

#pragma unroll
        for (int p = 0; p < NPTS; ++p) {
            const int lvl  = p >> 2;
            const int W    = (lvl == 0) ? 80 : (lvl == 1 ? 40 : 20);
            const int base = (lvl == 0) ? 0  : (lvl == 1 ? 6400 : 8000);

            const float ox = pr[h * 24 + p * 2 + 0];
            const float oy = pr[h * 24 + p * 2 + 1];
            // loc = ref_xy + off * (1/4) * ref_wh * 0.5 ; ix = loc*W - 0.5
            const float ix = (rx + ox * 0.125f * rw) * (float)W - 0.5f;
            const float iy = (ry + oy * 0.125f * rh) * (float)W - 0.5f;

            const float fx0 = floorf(ix), fy0 = floorf(iy);
            const int x0 = (int)fx0, y0 = (int)fy0;
            const float fx = ix - fx0, fy = iy - fy0;
            const float aw = a[p] * inv;

            const float w00 = aw * (1.f - fx) * (1.f - fy);
            const float w01 = aw * fx * (1.f - fy);
            const float w10 = aw * (1.f - fx) * fy;
            const float w11 = aw * fx * fy;

#pragma unroll
            for (int cnr = 0; cnr < 4; ++cnr) {
                const int x = x0 + (cnr & 1);
                const int y = y0 + (cnr >> 1);
                const float wgt = (cnr == 0) ? w00 : (cnr == 1) ? w01
                                 : (cnr == 2) ? w10 : w11;
                const int xc = min(max(x, 0), W - 1);
                const int yc = min(max(y, 0), W - 1);
                const bool ok = (x >= 0) & (x < W) & (y >= 0) & (y < W);
                const float wg = ok ? wgt : 0.f;
                const size_t cell = (size_t)(base + yc * W + xc) * (DM / 2);
                if (VF32) {
                    const float2 v = vb32[cell];
                    acc0 += wg * v.x;
                    acc1 += wg * v.y;
                } else {
                    const unsigned int v = vb16[cell];
                    acc0 += wg * bf2f((unsigned short)(v & 0xffffu));
                    acc1 += wg * bf2f((unsigned short)(v >> 16));
                }
            }
        }

        // fp32 output: element index bq*256 + h*32 + 2l (+1) -> float2 store
        out[(size_t)bq * (DM / 2) + h * (HD / 2) + l] = make_float2(acc0, acc1);
    }
}

// ---------------------------------------------------------------------------
// Fused kernel: one block per QB queries. No global workspace at all.
// ---------------------------------------------------------------------------
__global__ __launch_bounds__(256) void msda_fused(
    const void* __restrict__ query, const void* __restrict__ refp,
    const void* __restrict__ value, const void* __restrict__ Wo,
    const void* __restrict__ bo,    const void* __restrict__ Wa,
    const void* __restrict__ ba,    float2* __restrict__ out)
{
    __shared__ __align__(16) float q_lds[QB * DM];      // 8 KiB
    __shared__ float proj_lds[QB * NCOLS];              // 9 KiB
    __shared__ float ref_lds[QB * 4];
    __shared__ int s_flags;

    const int tid = threadIdx.x;
    const int q0  = blockIdx.x * QB;

    // phase 0: per-tensor dtype detection (wave 0 only)
    if (tid < 64) {
        int f = 0;
        if (vote_f32(query, tid)) f |= 1;
        if (vote_f32(refp,  tid)) f |= 2;
        if (vote_f32(value, tid)) f |= 4;
        if (vote_f32(Wo,    tid)) f |= 8;
        if (tid == 0) s_flags = f;
    }
    __syncthreads();
    const int fl = s_flags;

    // stage QB query rows (fp32) + QB ref points into LDS
    if (fl & 1) {
        for (int i = tid; i < QB * DM; i += 256)
            q_lds[i] = ((const float*)query)[q0 * DM + i];
    } else {
        for (int i = tid; i < QB * DM; i += 256)
            q_lds[i] = bf2f(((const unsigned short*)query)[q0 * DM + i]);
    }
    if (tid < QB * 4) {
        ref_lds[tid] = (fl & 2) ? ((const float*)refp)[q0 * 4 + tid]
                                : bf2f(((const unsigned short*)refp)[q0 * 4 + tid]);
    }
    __syncthreads();

    if (fl & 8) proj_cols<true >(Wo, bo, Wa, ba, q_lds, proj_lds, tid);
    else        proj_cols<false>(Wo, bo, Wa, ba, q_lds, proj_lds, tid);
    __syncthreads();

    if (fl & 4) sample_tasks<true >(value, proj_lds, ref_lds, out, q0, tid);
    else        sample_tasks<false>(value, proj_lds, ref_lds, out, q0, tid);
}

extern "C" void kernel_launch(void* const* d_in, const int* in_sizes, int n_in,
                              void* d_out, int out_size, void* d_ws, size_t ws_size,
                              hipStream_t stream) {
    const void* query = d_in[0];
    const void* refp  = d_in[1];
    const void* vflat = d_in[2];
    const void* Woff  = d_in[3];
    const void* boff  = d_in[4];
    const void* Wattn = d_in[5];
    const void* battn = d_in[6];
    float2* out = (float2*)d_out;
    (void)d_ws; (void)ws_size;

    msda_fused<<<dim3(NBLK), dim3(256), 0, stream>>>(
        query, refp, vflat, Woff, boff, Wattn, battn, out);
}

// Round 5
// 423.590 us; speedup vs baseline: 1.0713x; 1.0713x over previous
//
#include <hip/hip_runtime.h>

#define NB    32
#define LQ    300
#define DM    256
#define NH    8
#define NPTS  12
#define NCOLS 288   // 192 offset cols + 96 attn cols
#define STOT  8400
#define NBQ   (NB * LQ)

#define QB1   16    // queries per projection block
#define T1    320   // 5 waves; threads 288..319 idle after staging

// ---------------------------------------------------------------------------
// Kernel 1: projection. proj[bq][0:192] = q @ W_off + b_off
//                       proj[bq][192:288] = q @ W_attn + b_attn   (fp32)
// Thread j owns output column j for QB1 queries. W reads lane-contiguous
// (coalesced, L2-resident); query rows broadcast from LDS as float4.
// ---------------------------------------------------------------------------
__global__ __launch_bounds__(T1) void msda_proj(
    const float* __restrict__ query,   // (9600, 256)
    const float* __restrict__ Wo,      // (256, 192)
    const float* __restrict__ bo,      // (192)
    const float* __restrict__ Wa,      // (256, 96)
    const float* __restrict__ ba,      // (96)
    float* __restrict__ proj)          // (9600, 288)
{
    __shared__ __align__(16) float q_lds[QB1 * DM];   // 16 KiB
    const int tid = threadIdx.x;
    const int q0  = blockIdx.x * QB1;

    for (int i = tid; i < QB1 * DM; i += T1)
        q_lds[i] = query[(size_t)q0 * DM + i];
    __syncthreads();

    const int j = tid;
    if (j >= NCOLS) return;

    const float* Wp; const float* bp; int stride, jj;
    if (j < 192) { Wp = Wo; bp = bo; stride = 192; jj = j; }
    else         { Wp = Wa; bp = ba; stride = 96;  jj = j - 192; }

    float acc[QB1];
#pragma unroll
    for (int q = 0; q < QB1; ++q) acc[q] = 0.f;

    for (int k = 0; k < DM; k += 4) {
        float w0 = Wp[(k + 0) * stride + jj];
        float w1 = Wp[(k + 1) * stride + jj];
        float w2 = Wp[(k + 2) * stride + jj];
        float w3 = Wp[(k + 3) * stride + jj];
#pragma unroll
        for (int q = 0; q < QB1; ++q) {
            const float4 qv = *(const float4*)&q_lds[q * DM + k];
            acc[q] = fmaf(qv.x, w0,
                     fmaf(qv.y, w1,
                     fmaf(qv.z, w2,
                     fmaf(qv.w, w3, acc[q]))));
        }
    }

    const float bias = bp[jj];
#pragma unroll
    for (int q = 0; q < QB1; ++q)
        proj[(size_t)(q0 + q) * NCOLS + j] = acc[q] + bias;
}

// ---------------------------------------------------------------------------
// Kernel 2: softmax + bilinear sampling + weighted sum. Pure gather kernel:
// no LDS, no barriers. Thread = (bq, head h, lane l); lane owns 4 channels
// h*32 + 4l .. +3. 8 lanes/head-group -> 128B fully-utilized lines per
// corner gather. 48 independent float4 loads per thread, fully unrolled.
// ---------------------------------------------------------------------------
__global__ __launch_bounds__(256, 4) void msda_sample(
    const float* __restrict__ value,   // (B, 8400, 256)
    const float* __restrict__ refp,    // (B, LQ, 1, 4)
    const float* __restrict__ proj,    // (9600, 288)
    float4* __restrict__ out)          // (9600, 64) float4 view of (9600,256)
{
    const int gid = blockIdx.x * 256 + threadIdx.x;
    const int bq  = gid >> 6;
    const int h   = (gid >> 3) & 7;
    const int l   = gid & 7;
    const int b   = bq / LQ;

    const float* pr = proj + (size_t)bq * NCOLS;

    // softmax over the 12 attention logits of head h (redundant per 8 lanes)
    float a[NPTS];
#pragma unroll
    for (int p = 0; p < NPTS; ++p) a[p] = pr[192 + h * NPTS + p];
    float m = a[0];
#pragma unroll
    for (int p = 1; p < NPTS; ++p) m = fmaxf(m, a[p]);
    float s = 0.f;
#pragma unroll
    for (int p = 0; p < NPTS; ++p) { a[p] = __expf(a[p] - m); s += a[p]; }
    const float inv = 1.f / s;

    const float rx = refp[bq * 4 + 0];
    const float ry = refp[bq * 4 + 1];
    const float rw = refp[bq * 4 + 2];
    const float rh = refp[bq * 4 + 3];

    // float4 base for (b, cell 0, head h, channel block l)
    const float4* vb = (const float4*)value + ((size_t)b * STOT * 64 + h * 8 + l);

    float ax = 0.f, ay = 0.f, az = 0.f, aw4 = 0.f;

#pragma unroll
    for (int p = 0; p < NPTS; ++p) {
        const int lvl  = p >> 2;
        const int W    = (lvl == 0) ? 80 : (lvl == 1 ? 40 : 20);
        const int base = (lvl == 0) ? 0  : (lvl == 1 ? 6400 : 8000);

        const float ox = pr[h * 24 + p * 2 + 0];
        const float oy = pr[h * 24 + p * 2 + 1];
        // loc = ref_xy + off * (1/4) * ref_wh * 0.5 ; ix = loc*W - 0.5
        const float ix = fmaf(fmaf(ox, 0.125f * rw, rx), (float)W, -0.5f);
        const float iy = fmaf(fmaf(oy, 0.125f * rh, ry), (float)W, -0.5f);

        const float fx0 = floorf(ix), fy0 = floorf(iy);
        const int x0 = (int)fx0, y0 = (int)fy0;
        const float fx = ix - fx0, fy = iy - fy0;
        const float awt = a[p] * inv;

        const float w00 = awt * (1.f - fx) * (1.f - fy);
        const float w01 = awt * fx * (1.f - fy);
        const float w10 = awt * (1.f - fx) * fy;
        const float w11 = awt * fx * fy;

#pragma unroll
        for (int cnr = 0; cnr < 4; ++cnr) {
            const int x = x0 + (cnr & 1);
            const int y = y0 + (cnr >> 1);
            const float wgt = (cnr == 0) ? w00 : (cnr == 1) ? w01
                             : (cnr == 2) ? w10 : w11;
            const int xc = min(max(x, 0), W - 1);
            const int yc = min(max(y, 0), W - 1);
            const bool ok = (x >= 0) & (x < W) & (y >= 0) & (y < W);
            const float wg = ok ? wgt : 0.f;
            const float4 v = vb[(size_t)(base + yc * W + xc) * 64];
            ax  = fmaf(wg, v.x, ax);
            ay  = fmaf(wg, v.y, ay);
            az  = fmaf(wg, v.z, az);
            aw4 = fmaf(wg, v.w, aw4);
        }
    }

    out[(size_t)bq * 64 + h * 8 + l] = make_float4(ax, ay, az, aw4);
}

extern "C" void kernel_launch(void* const* d_in, const int* in_sizes, int n_in,
                              void* d_out, int out_size, void* d_ws, size_t ws_size,
                              hipStream_t stream) {
    const float* query = (const float*)d_in[0];
    const float* refp  = (const float*)d_in[1];
    const float* vflat = (const float*)d_in[2];
    const float* Woff  = (const float*)d_in[3];
    const float* boff  = (const float*)d_in[4];
    const float* Wattn = (const float*)d_in[5];
    const float* battn = (const float*)d_in[6];
    float4* out = (float4*)d_out;
    float* proj = (float*)d_ws;   // 9600*288*4 = 11.06 MB (ws >= 1.1 GB proven)

    msda_proj<<<dim3(NBQ / QB1), dim3(T1), 0, stream>>>(
        query, Woff, boff, Wattn, battn, proj);
    msda_sample<<<dim3(NBQ * 64 / 256), dim3(256), 0, stream>>>(
        vflat, refp, proj, out);
}